// Round 8
// baseline (192.656 us; speedup 1.0000x reference)
//
#include <hip/hip_runtime.h>
#include <math.h>

// ---------------- problem constants ----------------
// B=32, S=32, EMB=300, AUDIO=74, HID=128, D1=D2=16, DIM=256, UNITS=128, CELL=64

// ---------------- workspace layout (float offsets) ----------------
static constexpr unsigned XW0_OFF  = 0u;
static constexpr unsigned XW1_OFF  = 524288u;            // 1024*512
static constexpr unsigned XMAT_OFF = 1179648u;
static constexpr unsigned WT_OFF   = XMAT_OFF + 524288u; // 1703936
static constexpr unsigned VPP_OFF  = WT_OFF + 1024u;     // 1704960
static constexpr unsigned PP_OFF   = VPP_OFF + 131072u;  // 1836032
static constexpr unsigned PP_HALF  = 262144u;            // 1024*256

// stage[] LDS float offsets (epilogue weight staging)
static constexpr int WLIN = 0;       // 16x128
static constexpr int W1O  = 2048;    // 16x74
static constexpr int W2O  = 3232;    // 16x16
static constexpr int W3O  = 3488;    // 16x16
static constexpr int AUDO = 3744;    // 32x74 (this batch)
static constexpr int BLIN = 6112;    // 16
static constexpr int B1O  = 6128;
static constexpr int B2O  = 6144;
static constexpr int B3O  = 6160;    // total 6176 floats = 1544 float4

// =====================================================================
// K1: xw[r][j] = sum_k lut[word[r]][k] * w_ih[j][k]  (+ b_ih + b_hh on kq==0)
//     bid <  256 : GEMM 64x64 tiles, 4x4 micro, k split [0,152)/[152,300).
//     bid >= 256 : V'' builder, one block per unit u (128 blocks).
// =====================================================================
__global__ __launch_bounds__(256) void k1_xw_gemm(
    const int* __restrict__ widx, const float* __restrict__ lut,
    const float* __restrict__ w_ih, const float* __restrict__ b_ih,
    const float* __restrict__ b_hh,
    const float* __restrict__ mr, const float* __restrict__ mi,
    float* __restrict__ ws)
{
  const int bid = blockIdx.x;
  const int t = threadIdx.x;

  if (bid >= 256) {
    const int u = bid - 256;                 // 0..127
    float r  = mr[u * 256 + t];
    float ii = mi[u * 256 + t];
    float sq = r * r + ii * ii;
    #pragma unroll
    for (int off = 1; off < 64; off <<= 1) sq += __shfl_xor(sq, off);
    __shared__ float wsum[4];
    if ((t & 63) == 0) wsum[t >> 6] = sq;
    __syncthreads();
    float tot = wsum[0] + wsum[1] + wsum[2] + wsum[3];
    float inv = 1.0f / (sqrtf(tot) + 1e-10f);
    float vr = r * inv, vi = ii * inv;
    float* vpp = ws + VPP_OFF;
    vpp[(2 * u) * 512 + t]           = vr;
    vpp[(2 * u) * 512 + 256 + t]     = vi;
    vpp[(2 * u + 1) * 512 + t]       = -vi;
    vpp[(2 * u + 1) * 512 + 256 + t] = vr;
    return;
  }

  const int rb = bid & 15, cb = (bid >> 4) & 7, kq = bid >> 7;
  const int R = rb * 64, C = cb * 64;
  const int kbase_g = kq * 152;
  const int ktot = kq ? 148 : 152;

  __shared__ alignas(16) float As[32][68];
  __shared__ alignas(16) float Ws[32][68];

  float acc[4][4] = {};
  const int r0 = (t & 15) * 4, j0 = (t >> 4) * 4;

  for (int kt = 0; kt < 5; ++kt) {
    int kl = ktot - kt * 32; if (kl > 32) kl = 32;
    #pragma unroll
    for (int pass = 0; pass < 2; ++pass) {
      int rr = (t >> 3) + pass * 32;
      int kk4 = (t & 7) * 4;
      float4 av = make_float4(0.f, 0.f, 0.f, 0.f);
      float4 wv = make_float4(0.f, 0.f, 0.f, 0.f);
      if (kk4 < kl) {
        int gk = kbase_g + kt * 32 + kk4;
        int word = widx[R + rr];
        av = *(const float4*)&lut[word * 300 + gk];
        wv = *(const float4*)&w_ih[(C + rr) * 300 + gk];
      }
      As[kk4 + 0][rr] = av.x; As[kk4 + 1][rr] = av.y;
      As[kk4 + 2][rr] = av.z; As[kk4 + 3][rr] = av.w;
      Ws[kk4 + 0][rr] = wv.x; Ws[kk4 + 1][rr] = wv.y;
      Ws[kk4 + 2][rr] = wv.z; Ws[kk4 + 3][rr] = wv.w;
    }
    __syncthreads();
    #pragma unroll
    for (int k = 0; k < 32; ++k) {
      float4 a4 = *(const float4*)&As[k][r0];
      float4 w4 = *(const float4*)&Ws[k][j0];
      float ar[4] = {a4.x, a4.y, a4.z, a4.w};
      float wr[4] = {w4.x, w4.y, w4.z, w4.w};
      #pragma unroll
      for (int i2 = 0; i2 < 4; ++i2)
        #pragma unroll
        for (int j2 = 0; j2 < 4; ++j2)
          acc[i2][j2] = fmaf(ar[i2], wr[j2], acc[i2][j2]);
    }
    __syncthreads();
  }

  float* xw = ws + (kq ? XW1_OFF : XW0_OFF);
  #pragma unroll
  for (int i2 = 0; i2 < 4; ++i2) {
    int row = R + r0 + i2, col = C + j0;
    float4 v = make_float4(acc[i2][0], acc[i2][1], acc[i2][2], acc[i2][3]);
    if (kq == 0) {
      v.x += b_ih[col + 0] + b_hh[col + 0];
      v.y += b_ih[col + 1] + b_hh[col + 1];
      v.z += b_ih[col + 2] + b_hh[col + 2];
      v.w += b_ih[col + 3] + b_hh[col + 3];
    }
    *(float4*)&xw[row * 512 + col] = v;
  }
}

// =====================================================================
// K2'': LSTM + fused mix. One block per batch, 512 threads = 8 SYMMETRIC
//   waves, ONE barrier per step (round-7 had 65 heterogeneous-wave
//   barriers = the convoy cost).
//   Wave wv owns k-slice [wv*16,+16). Lane l holds weights for output
//   units {l, 64+l} x 4 gates (128 VGPRs). Per step:
//     reduce: lanes 0-15 reduce part[s&1][0..8] for unit wv*16+l (the
//       only h values this wave needs!), + prefetched xw, exp chain,
//       ds_write hist[s+1][own unit] — read back WAVE-LOCALLY (same-wave
//       DS ops are in-order; no barrier).
//     dot:    all lanes, broadcast-read own slice of hist[s+1], FMA into
//       part[(s+1)&1] (double buffer = write-after-read safe).
//     barrier.
//   Epilogue: w_lin/w1/w2/w3/biases/audio staged to LDS with coalesced
//   float4s (round-7 epilogue did 200+ scalar global loads per thread
//   = the 23us regression), then identical math order as before.
// =====================================================================
__global__ __launch_bounds__(512, 2) void k2_lstm_mix(
    const float* __restrict__ w_hh, const int* __restrict__ widx,
    const float* __restrict__ audio,
    const float* __restrict__ ph0t, const float* __restrict__ ph1t,
    const float* __restrict__ w_lin, const float* __restrict__ b_lin,
    const float* __restrict__ w1, const float* __restrict__ b1,
    const float* __restrict__ w2, const float* __restrict__ b2,
    const float* __restrict__ w3, const float* __restrict__ b3,
    const float* __restrict__ modw, float* __restrict__ ws)
{
  const int b = blockIdx.x;
  const int t = threadIdx.x;
  const int wv = t >> 6;      // 0..7
  const int l  = t & 63;

  __shared__ alignas(16) float part[2][8][512];
  __shared__ alignas(16) float hist[33][132];   // pad 132: 528B rows, 16B-aligned
  __shared__ float stage[6176];
  __shared__ float amp0s[32][17], a1s[32][17], a2s[32][17], amp1s[32][17];
  __shared__ float tprs[32][17], tpis[32][17], r1ss[32][17], i1ss[32][17];
  __shared__ float nrm0[32], nrm1[32];

  const float* xw0 = ws + XW0_OFF;
  const float* xw1 = ws + XW1_OFF;

  // weights: lane owns units uA=l, uB=64+l, k-slice wv*16..+16
  float4 wA[4][4], wB[4][4];
  #pragma unroll
  for (int g = 0; g < 4; ++g) {
    const float* pA = w_hh + (g * 128 + l) * 128 + wv * 16;
    const float* pB = w_hh + (g * 128 + 64 + l) * 128 + wv * 16;
    #pragma unroll
    for (int c = 0; c < 4; ++c) {
      wA[g][c] = *(const float4*)&pA[c * 4];
      wB[g][c] = *(const float4*)&pB[c * 4];
    }
  }

  const int ju = wv * 16 + (l & 15);     // reduce-phase unit (lanes<16)
  float c = 0.f;
  float x0 = 0.f, x1 = 0.f, x2 = 0.f, x3 = 0.f;
  if (l < 16) {                          // prefetch xw for s=0
    const int base = (b * 32 + 0) * 512 + ju;
    x0 = xw0[base +   0] + xw1[base +   0];
    x1 = xw0[base + 128] + xw1[base + 128];
    x2 = xw0[base + 256] + xw1[base + 256];
    x3 = xw0[base + 384] + xw1[base + 384];
  }
  if (t < 128) hist[0][t] = 0.f;
  __syncthreads();                       // hist[0] visible to all waves

  // prologue: partials for s=0 from hist[0]
  {
    const float* hb = &hist[0][wv * 16];
    float aA0=0.f,aA1=0.f,aA2=0.f,aA3=0.f,aB0=0.f,aB1=0.f,aB2=0.f,aB3=0.f;
    #pragma unroll
    for (int cc = 0; cc < 4; ++cc) {
      float4 h4 = *(const float4*)&hb[cc * 4];
      aA0 = fmaf(wA[0][cc].x, h4.x, fmaf(wA[0][cc].y, h4.y, fmaf(wA[0][cc].z, h4.z, fmaf(wA[0][cc].w, h4.w, aA0))));
      aA1 = fmaf(wA[1][cc].x, h4.x, fmaf(wA[1][cc].y, h4.y, fmaf(wA[1][cc].z, h4.z, fmaf(wA[1][cc].w, h4.w, aA1))));
      aA2 = fmaf(wA[2][cc].x, h4.x, fmaf(wA[2][cc].y, h4.y, fmaf(wA[2][cc].z, h4.z, fmaf(wA[2][cc].w, h4.w, aA2))));
      aA3 = fmaf(wA[3][cc].x, h4.x, fmaf(wA[3][cc].y, h4.y, fmaf(wA[3][cc].z, h4.z, fmaf(wA[3][cc].w, h4.w, aA3))));
      aB0 = fmaf(wB[0][cc].x, h4.x, fmaf(wB[0][cc].y, h4.y, fmaf(wB[0][cc].z, h4.z, fmaf(wB[0][cc].w, h4.w, aB0))));
      aB1 = fmaf(wB[1][cc].x, h4.x, fmaf(wB[1][cc].y, h4.y, fmaf(wB[1][cc].z, h4.z, fmaf(wB[1][cc].w, h4.w, aB1))));
      aB2 = fmaf(wB[2][cc].x, h4.x, fmaf(wB[2][cc].y, h4.y, fmaf(wB[2][cc].z, h4.z, fmaf(wB[2][cc].w, h4.w, aB2))));
      aB3 = fmaf(wB[3][cc].x, h4.x, fmaf(wB[3][cc].y, h4.y, fmaf(wB[3][cc].z, h4.z, fmaf(wB[3][cc].w, h4.w, aB3))));
    }
    *(float4*)&part[0][wv][l * 4]       = make_float4(aA0, aA1, aA2, aA3);
    *(float4*)&part[0][wv][256 + l * 4] = make_float4(aB0, aB1, aB2, aB3);
  }
  __syncthreads();                       // part[0] complete

  for (int s = 0; s < 32; ++s) {
    // ---- reduce (lanes 0-15 of each wave; own 16 units only) ----
    if (l < 16) {
      float g0 = x0, g1 = x1, g2 = x2, g3 = x3;
      #pragma unroll
      for (int w = 0; w < 8; ++w) {
        float4 p = *(const float4*)&part[s & 1][w][ju * 4];
        g0 += p.x; g1 += p.y; g2 += p.z; g3 += p.w;
      }
      float si = 1.f / (1.f + __expf(-g0));
      float sf = 1.f / (1.f + __expf(-g1));
      float tg = 1.f - 2.f / (1.f + __expf(2.f * g2));
      float so = 1.f / (1.f + __expf(-g3));
      c = sf * c + si * tg;
      float tc = 1.f - 2.f / (1.f + __expf(2.f * c));
      hist[s + 1][ju] = so * tc;
      if (s < 31) {                      // prefetch next xw
        const int nb = (b * 32 + s + 1) * 512 + ju;
        x0 = xw0[nb +   0] + xw1[nb +   0];
        x1 = xw0[nb + 128] + xw1[nb + 128];
        x2 = xw0[nb + 256] + xw1[nb + 256];
        x3 = xw0[nb + 384] + xw1[nb + 384];
      }
    }
    // ---- dot for step s+1 (all lanes; reads own-wave hist writes) ----
    if (s < 31) {
      const float* hb = &hist[s + 1][wv * 16];
      float aA0=0.f,aA1=0.f,aA2=0.f,aA3=0.f,aB0=0.f,aB1=0.f,aB2=0.f,aB3=0.f;
      #pragma unroll
      for (int cc = 0; cc < 4; ++cc) {
        float4 h4 = *(const float4*)&hb[cc * 4];
        aA0 = fmaf(wA[0][cc].x, h4.x, fmaf(wA[0][cc].y, h4.y, fmaf(wA[0][cc].z, h4.z, fmaf(wA[0][cc].w, h4.w, aA0))));
        aA1 = fmaf(wA[1][cc].x, h4.x, fmaf(wA[1][cc].y, h4.y, fmaf(wA[1][cc].z, h4.z, fmaf(wA[1][cc].w, h4.w, aA1))));
        aA2 = fmaf(wA[2][cc].x, h4.x, fmaf(wA[2][cc].y, h4.y, fmaf(wA[2][cc].z, h4.z, fmaf(wA[2][cc].w, h4.w, aA2))));
        aA3 = fmaf(wA[3][cc].x, h4.x, fmaf(wA[3][cc].y, h4.y, fmaf(wA[3][cc].z, h4.z, fmaf(wA[3][cc].w, h4.w, aA3))));
        aB0 = fmaf(wB[0][cc].x, h4.x, fmaf(wB[0][cc].y, h4.y, fmaf(wB[0][cc].z, h4.z, fmaf(wB[0][cc].w, h4.w, aB0))));
        aB1 = fmaf(wB[1][cc].x, h4.x, fmaf(wB[1][cc].y, h4.y, fmaf(wB[1][cc].z, h4.z, fmaf(wB[1][cc].w, h4.w, aB1))));
        aB2 = fmaf(wB[2][cc].x, h4.x, fmaf(wB[2][cc].y, h4.y, fmaf(wB[2][cc].z, h4.z, fmaf(wB[2][cc].w, h4.w, aB2))));
        aB3 = fmaf(wB[3][cc].x, h4.x, fmaf(wB[3][cc].y, h4.y, fmaf(wB[3][cc].z, h4.z, fmaf(wB[3][cc].w, h4.w, aB3))));
      }
      *(float4*)&part[(s + 1) & 1][wv][l * 4]       = make_float4(aA0, aA1, aA2, aA3);
      *(float4*)&part[(s + 1) & 1][wv][256 + l * 4] = make_float4(aB0, aB1, aB2, aB3);
    }
    __syncthreads();                     // ONE barrier per step
  }

  // ================= staged mix epilogue =================
  const int word_base = b * 32;
  // stage 1544 float4s: [w_lin|w1|w2|w3|audio_b|b_lin b1 b2 b3]
  for (int i = t; i < 1544; i += 512) {
    const float* src;
    if (i < 512)       src = w_lin + i * 4;
    else if (i < 808)  src = w1 + (i - 512) * 4;
    else if (i < 872)  src = w2 + (i - 808) * 4;
    else if (i < 936)  src = w3 + (i - 872) * 4;
    else if (i < 1528) src = audio + word_base * 74 + (i - 936) * 4;
    else {
      int j = i - 1528;
      const float* bsrc = (j < 4) ? b_lin : (j < 8) ? b1 : (j < 12) ? b2 : b3;
      src = bsrc + (j & 3) * 4;
    }
    *(float4*)&stage[i * 4] = *(const float4*)src;
  }
  __syncthreads();

  const int s = t >> 4, d = t & 15;
  {
    float acc = stage[BLIN + d];
    const float* wl = &stage[WLIN + d * 128];
    const float* hh = &hist[s + 1][0];
    for (int u = 0; u < 128; ++u) acc = fmaf(hh[u], wl[u], acc);
    amp0s[s][d] = acc;
    float a = stage[B1O + d];
    const float* au = &stage[AUDO + s * 74];
    const float* w1r = &stage[W1O + d * 74];
    for (int k = 0; k < 74; ++k) a = fmaf(au[k], w1r[k], a);
    a1s[s][d] = fmaxf(a, 0.f);
  }
  __syncthreads();
  {
    float a = stage[B2O + d];
    #pragma unroll
    for (int k = 0; k < 16; ++k) a = fmaf(a1s[s][k], stage[W2O + d * 16 + k], a);
    a2s[s][d] = fmaxf(a, 0.f);
  }
  __syncthreads();
  {
    float a = stage[B3O + d];
    #pragma unroll
    for (int k = 0; k < 16; ++k) a = fmaf(a2s[s][k], stage[W3O + d * 16 + k], a);
    amp1s[s][d] = fmaxf(a, 0.f);
  }
  __syncthreads();
  if (t < 32) {
    float sq = 0.f;
    #pragma unroll
    for (int dd = 0; dd < 16; ++dd) sq += amp0s[t][dd] * amp0s[t][dd];
    nrm0[t] = sqrtf(sq);
  } else if (t >= 64 && t < 96) {
    int ss = t - 64;
    float sq = 0.f;
    #pragma unroll
    for (int dd = 0; dd < 16; ++dd) sq += amp1s[ss][dd] * amp1s[ss][dd];
    nrm1[ss] = sqrtf(sq);
  }
  __syncthreads();
  {
    const int word = widx[word_base + s];
    float k0 = amp0s[s][d] / (nrm0[s] + 1e-10f);
    float ph = ph0t[word * 16 + d];
    float cc = cosf(ph), sn = sinf(ph);
    tprs[s][d] = k0 * (cc - sn);        // r0 - i0
    tpis[s][d] = k0 * (cc + sn);        // r0 + i0
    float k1v = amp1s[s][d] / (nrm1[s] + 1e-10f);
    float p1 = ph1t[word * 16 + d];
    r1ss[s][d] = k1v * cosf(p1);
    i1ss[s][d] = k1v * sinf(p1);
    if (d == 0) {
      float e0 = __expf(modw[0]), e1 = __expf(modw[1]);
      float mw0 = e0 / (e0 + e1);
      ws[WT_OFF + word_base + s] = mw0 * nrm0[s] + (1.f - mw0) * nrm1[s];
    }
  }
  __syncthreads();
  {
    float* X = ws + XMAT_OFF;
    const int c2 = t;                    // column 0..511
    const int half = c2 >> 8;            // 0 = real, 1 = imag
    const int i2 = (c2 >> 4) & 15, j2 = c2 & 15;
    for (int ss = 0; ss < 32; ++ss) {
      float v;
      if (half == 0) v = tprs[ss][i2] * r1ss[ss][j2] - tpis[ss][i2] * i1ss[ss][j2];
      else           v = tprs[ss][i2] * i1ss[ss][j2] + tpis[ss][i2] * r1ss[ss][j2];
      X[(word_base + ss) * 512 + c2] = v;
    }
  }
}

// =====================================================================
// K4: P[r][c] = sum_k X[r][k] * V''[c][k]   (1024 x 256, k=512 split x4)
// =====================================================================
__global__ __launch_bounds__(256) void k4_meas(float* __restrict__ ws)
{
  const int bid = blockIdx.x, t = threadIdx.x;
  const int rb = bid & 15, cb = (bid >> 4) & 3, kq = bid >> 6;
  const int R = rb * 64, C = cb * 64;
  const float* X = ws + XMAT_OFF;
  const float* V = ws + VPP_OFF;
  __shared__ alignas(16) float Xs[32][68];
  __shared__ alignas(16) float Vs[32][68];
  float acc[4][4] = {};
  const int r0 = (t & 15) * 4, j0 = (t >> 4) * 4;

  for (int kt = 0; kt < 4; ++kt) {
    #pragma unroll
    for (int pass = 0; pass < 2; ++pass) {
      int rr = (t >> 3) + pass * 32;
      int kk4 = (t & 7) * 4;
      int gk = kq * 128 + kt * 32 + kk4;
      float4 xv = *(const float4*)&X[(R + rr) * 512 + gk];
      float4 vv = *(const float4*)&V[(C + rr) * 512 + gk];
      Xs[kk4 + 0][rr] = xv.x; Xs[kk4 + 1][rr] = xv.y;
      Xs[kk4 + 2][rr] = xv.z; Xs[kk4 + 3][rr] = xv.w;
      Vs[kk4 + 0][rr] = vv.x; Vs[kk4 + 1][rr] = vv.y;
      Vs[kk4 + 2][rr] = vv.z; Vs[kk4 + 3][rr] = vv.w;
    }
    __syncthreads();
    #pragma unroll
    for (int k = 0; k < 32; ++k) {
      float4 a4 = *(const float4*)&Xs[k][r0];
      float4 w4 = *(const float4*)&Vs[k][j0];
      float ar[4] = {a4.x, a4.y, a4.z, a4.w};
      float wr[4] = {w4.x, w4.y, w4.z, w4.w};
      #pragma unroll
      for (int i2 = 0; i2 < 4; ++i2)
        #pragma unroll
        for (int j2 = 0; j2 < 4; ++j2)
          acc[i2][j2] = fmaf(ar[i2], wr[j2], acc[i2][j2]);
    }
    __syncthreads();
  }
  float* Pp = ws + PP_OFF + (unsigned)kq * PP_HALF;
  #pragma unroll
  for (int i2 = 0; i2 < 4; ++i2) {
    float4 v = make_float4(acc[i2][0], acc[i2][1], acc[i2][2], acc[i2][3]);
    *(float4*)&Pp[(R + r0 + i2) * 256 + C + j0] = v;
  }
}

// =====================================================================
// K5: per b: p[s][u] = P[2u]^2 + P[2u+1]^2 (sum kq partials);
//     n-gram softmax mixes (n=1,3 zero-padded), max-pool, final MLP.
// =====================================================================
__global__ __launch_bounds__(512) void k5_final(
    const float* __restrict__ fw1, const float* __restrict__ fb1,
    const float* __restrict__ fw2, const float* __restrict__ fb2,
    const float* __restrict__ fw3, const float* __restrict__ fb3,
    const float* __restrict__ ws, float* __restrict__ out)
{
  const int b = blockIdx.x, t = threadIdx.x;
  const int u = t & 127, sg = t >> 7;      // sg 0..3
  __shared__ float ewt[34];
  __shared__ float pl[32][128];
  __shared__ float fred[4][128];
  __shared__ float feat[128], y1[64], y2[64];
  if (t < 32) ewt[t] = __expf(ws[WT_OFF + b * 32 + t]);
  if (t >= 32 && t < 34) ewt[t] = 1.f;
  __syncthreads();

  const float* Pp = ws + PP_OFF;
  #pragma unroll
  for (int i = 0; i < 8; ++i) {
    int s = sg * 8 + i;
    int bs = b * 32 + s;
    float A = 0.f, Bv = 0.f;
    #pragma unroll
    for (int kq = 0; kq < 4; ++kq) {
      A  += Pp[kq * PP_HALF + bs * 256 + 2 * u];
      Bv += Pp[kq * PP_HALF + bs * 256 + 2 * u + 1];
    }
    pl[s][u] = A * A + Bv * Bv;
  }
  __syncthreads();

  float m = -1e30f;
  #pragma unroll
  for (int i = 0; i < 8; ++i) {
    int s = sg * 8 + i;
    float p0 = pl[s][u];
    m = fmaxf(m, p0);
    float e0 = ewt[s], e1 = ewt[s + 1], e2 = ewt[s + 2];
    float num = e0 * p0;
    if (s + 1 < 32) num += e1 * pl[s + 1][u];
    if (s + 2 < 32) num += e2 * pl[s + 2][u];
    m = fmaxf(m, num / (e0 + e1 + e2));
  }
  fred[sg][u] = m;
  __syncthreads();
  if (t < 128)
    feat[t] = fmaxf(fmaxf(fred[0][t], fred[1][t]), fmaxf(fred[2][t], fred[3][t]));
  __syncthreads();
  if (t < 64) {
    float acc = fb1[t];
    for (int k = 0; k < 128; ++k) acc = fmaf(feat[k], fw1[t * 128 + k], acc);
    y1[t] = fmaxf(acc, 0.f);
  }
  __syncthreads();
  if (t < 64) {
    float acc = fb2[t];
    #pragma unroll
    for (int k = 0; k < 64; ++k) acc = fmaf(y1[k], fw2[t * 64 + k], acc);
    y2[t] = fmaxf(acc, 0.f);
  }
  __syncthreads();
  if (t == 0) {
    float acc = fb3[0];
    #pragma unroll
    for (int k = 0; k < 64; ++k) acc = fmaf(y2[k], fw3[k], acc);
    out[b] = acc;
  }
}

// =====================================================================
extern "C" void kernel_launch(void* const* d_in, const int* in_sizes, int n_in,
                              void* d_out, int out_size, void* d_ws, size_t ws_size,
                              hipStream_t stream) {
  const int*   widx  = (const int*)d_in[0];
  const float* audio = (const float*)d_in[1];
  const float* lut   = (const float*)d_in[2];
  const float* ph0   = (const float*)d_in[3];
  const float* ph1   = (const float*)d_in[4];
  const float* w_ih  = (const float*)d_in[5];
  const float* w_hh  = (const float*)d_in[6];
  const float* b_ih  = (const float*)d_in[7];
  const float* b_hh  = (const float*)d_in[8];
  const float* w_lin = (const float*)d_in[9];
  const float* b_lin = (const float*)d_in[10];
  const float* w1    = (const float*)d_in[11];
  const float* b1    = (const float*)d_in[12];
  const float* w2    = (const float*)d_in[13];
  const float* b2    = (const float*)d_in[14];
  const float* w3    = (const float*)d_in[15];
  const float* b3    = (const float*)d_in[16];
  const float* modw  = (const float*)d_in[17];
  const float* mr    = (const float*)d_in[18];
  const float* mi    = (const float*)d_in[19];
  const float* fw1   = (const float*)d_in[20];
  const float* fb1   = (const float*)d_in[21];
  const float* fw2   = (const float*)d_in[22];
  const float* fb2   = (const float*)d_in[23];
  const float* fw3   = (const float*)d_in[24];
  const float* fb3   = (const float*)d_in[25];
  float* ws  = (float*)d_ws;
  float* out = (float*)d_out;

  k1_xw_gemm<<<dim3(384), dim3(256), 0, stream>>>(widx, lut, w_ih, b_ih, b_hh, mr, mi, ws);
  k2_lstm_mix<<<dim3(32), dim3(512), 0, stream>>>(w_hh, widx, audio, ph0, ph1,
                                                  w_lin, b_lin, w1, b1, w2, b2,
                                                  w3, b3, modw, ws);
  k4_meas<<<dim3(256), dim3(256), 0, stream>>>(ws);
  k5_final<<<dim3(32), dim3(512), 0, stream>>>(fw1, fb1, fw2, fb2, fw3, fb3, ws, out);
}

// Round 9
// 186.919 us; speedup vs baseline: 1.0307x; 1.0307x over previous
//
#include <hip/hip_runtime.h>
#include <math.h>

// ---------------- problem constants ----------------
// B=32, S=32, EMB=300, AUDIO=74, HID=128, D1=D2=16, DIM=256, UNITS=128, CELL=64

// ---------------- workspace layout (float offsets) ----------------
static constexpr unsigned XW0_OFF  = 0u;
static constexpr unsigned XW1_OFF  = 524288u;            // 1024*512
static constexpr unsigned XMAT_OFF = 1179648u;
static constexpr unsigned WT_OFF   = XMAT_OFF + 524288u; // 1703936
static constexpr unsigned VPP_OFF  = WT_OFF + 1024u;     // 1704960
static constexpr unsigned PP_OFF   = VPP_OFF + 131072u;  // 1836032
static constexpr unsigned PP_HALF  = 262144u;            // 1024*256

// stage[] LDS float offsets (epilogue staging; w_lin lives in wlT separately)
static constexpr int W1O  = 0;       // 16x74
static constexpr int W2O  = 1184;    // 16x16
static constexpr int W3O  = 1440;    // 16x16
static constexpr int AUDO = 1696;    // 32x74 (this batch)
static constexpr int BLIN = 4064;    // 16
static constexpr int B1O  = 4080;
static constexpr int B2O  = 4096;
static constexpr int B3O  = 4112;    // total 4128 floats = 1032 float4

__device__ __forceinline__ float readl(float v, int lane) {
  return __uint_as_float(__builtin_amdgcn_readlane(__float_as_uint(v), lane));
}

// =====================================================================
// K1: xw[r][j] = sum_k lut[word[r]][k] * w_ih[j][k]  (+ b_ih + b_hh on kq==0)
//     bid <  256 : GEMM 64x64 tiles, 4x4 micro, k split [0,152)/[152,300).
//     bid >= 256 : V'' builder, one block per unit u (128 blocks).
// =====================================================================
__global__ __launch_bounds__(256) void k1_xw_gemm(
    const int* __restrict__ widx, const float* __restrict__ lut,
    const float* __restrict__ w_ih, const float* __restrict__ b_ih,
    const float* __restrict__ b_hh,
    const float* __restrict__ mr, const float* __restrict__ mi,
    float* __restrict__ ws)
{
  const int bid = blockIdx.x;
  const int t = threadIdx.x;

  if (bid >= 256) {
    const int u = bid - 256;                 // 0..127
    float r  = mr[u * 256 + t];
    float ii = mi[u * 256 + t];
    float sq = r * r + ii * ii;
    #pragma unroll
    for (int off = 1; off < 64; off <<= 1) sq += __shfl_xor(sq, off);
    __shared__ float wsum[4];
    if ((t & 63) == 0) wsum[t >> 6] = sq;
    __syncthreads();
    float tot = wsum[0] + wsum[1] + wsum[2] + wsum[3];
    float inv = 1.0f / (sqrtf(tot) + 1e-10f);
    float vr = r * inv, vi = ii * inv;
    float* vpp = ws + VPP_OFF;
    vpp[(2 * u) * 512 + t]           = vr;
    vpp[(2 * u) * 512 + 256 + t]     = vi;
    vpp[(2 * u + 1) * 512 + t]       = -vi;
    vpp[(2 * u + 1) * 512 + 256 + t] = vr;
    return;
  }

  const int rb = bid & 15, cb = (bid >> 4) & 7, kq = bid >> 7;
  const int R = rb * 64, C = cb * 64;
  const int kbase_g = kq * 152;
  const int ktot = kq ? 148 : 152;

  __shared__ alignas(16) float As[32][68];
  __shared__ alignas(16) float Ws[32][68];

  float acc[4][4] = {};
  const int r0 = (t & 15) * 4, j0 = (t >> 4) * 4;

  for (int kt = 0; kt < 5; ++kt) {
    int kl = ktot - kt * 32; if (kl > 32) kl = 32;
    #pragma unroll
    for (int pass = 0; pass < 2; ++pass) {
      int rr = (t >> 3) + pass * 32;
      int kk4 = (t & 7) * 4;
      float4 av = make_float4(0.f, 0.f, 0.f, 0.f);
      float4 wv = make_float4(0.f, 0.f, 0.f, 0.f);
      if (kk4 < kl) {
        int gk = kbase_g + kt * 32 + kk4;
        int word = widx[R + rr];
        av = *(const float4*)&lut[word * 300 + gk];
        wv = *(const float4*)&w_ih[(C + rr) * 300 + gk];
      }
      As[kk4 + 0][rr] = av.x; As[kk4 + 1][rr] = av.y;
      As[kk4 + 2][rr] = av.z; As[kk4 + 3][rr] = av.w;
      Ws[kk4 + 0][rr] = wv.x; Ws[kk4 + 1][rr] = wv.y;
      Ws[kk4 + 2][rr] = wv.z; Ws[kk4 + 3][rr] = wv.w;
    }
    __syncthreads();
    #pragma unroll
    for (int k = 0; k < 32; ++k) {
      float4 a4 = *(const float4*)&As[k][r0];
      float4 w4 = *(const float4*)&Ws[k][j0];
      float ar[4] = {a4.x, a4.y, a4.z, a4.w};
      float wr[4] = {w4.x, w4.y, w4.z, w4.w};
      #pragma unroll
      for (int i2 = 0; i2 < 4; ++i2)
        #pragma unroll
        for (int j2 = 0; j2 < 4; ++j2)
          acc[i2][j2] = fmaf(ar[i2], wr[j2], acc[i2][j2]);
    }
    __syncthreads();
  }

  float* xw = ws + (kq ? XW1_OFF : XW0_OFF);
  #pragma unroll
  for (int i2 = 0; i2 < 4; ++i2) {
    int row = R + r0 + i2, col = C + j0;
    float4 v = make_float4(acc[i2][0], acc[i2][1], acc[i2][2], acc[i2][3]);
    if (kq == 0) {
      v.x += b_ih[col + 0] + b_hh[col + 0];
      v.y += b_ih[col + 1] + b_hh[col + 1];
      v.z += b_ih[col + 2] + b_hh[col + 2];
      v.w += b_ih[col + 3] + b_hh[col + 3];
    }
    *(float4*)&xw[row * 512 + col] = v;
  }
}

// =====================================================================
// K2''': LSTM + fused mix. 512 threads = 8 symmetric waves, ONE barrier
//   per step, and NO hist LDS round-trip on the critical path:
//   wave wv's dot needs only h[wv*16..+16] — exactly what its own lanes
//   0-15 computed — so h is broadcast via v_readlane (SGPR operands),
//   deleting one ~120-cyc LDS latency hop per step (round-8 analysis).
//   hist writes remain but are epilogue-only (off critical path).
//   part[0] zero-init replaces the h(0)=0 prologue dot (bitwise same).
//   Epilogue: w_lin staged TRANSPOSED+padded (wlT[u*17+d]) — round-8's
//   stride-128 layout was a 16-way bank conflict on every read (521k
//   conflict cycles); w1 (74≡10d: 16 distinct banks) & w2/w3 (2-way,
//   free) verified fine.
// =====================================================================
__global__ __launch_bounds__(512, 1) void k2_lstm_mix(
    const float* __restrict__ w_hh, const int* __restrict__ widx,
    const float* __restrict__ audio,
    const float* __restrict__ ph0t, const float* __restrict__ ph1t,
    const float* __restrict__ w_lin, const float* __restrict__ b_lin,
    const float* __restrict__ w1, const float* __restrict__ b1,
    const float* __restrict__ w2, const float* __restrict__ b2,
    const float* __restrict__ w3, const float* __restrict__ b3,
    const float* __restrict__ modw, float* __restrict__ ws)
{
  const int b = blockIdx.x;
  const int t = threadIdx.x;
  const int wv = t >> 6;      // 0..7
  const int l  = t & 63;

  __shared__ alignas(16) float part[2][8][512];
  __shared__ alignas(16) float hist[32][132];   // hist[s] = h after step s
  __shared__ float wlT[2176];                   // w_lin transposed, pad 17
  __shared__ float stage[4128];
  __shared__ float amp0s[32][17], a1s[32][17], a2s[32][17], amp1s[32][17];
  __shared__ float tprs[32][17], tpis[32][17], r1ss[32][17], i1ss[32][17];
  __shared__ float nrm0[32], nrm1[32];

  const float* xw0 = ws + XW0_OFF;
  const float* xw1 = ws + XW1_OFF;

  // weights: lane owns units uA=l, uB=64+l, k-slice wv*16..+16
  float4 wA[4][4], wB[4][4];
  #pragma unroll
  for (int g = 0; g < 4; ++g) {
    const float* pA = w_hh + (g * 128 + l) * 128 + wv * 16;
    const float* pB = w_hh + (g * 128 + 64 + l) * 128 + wv * 16;
    #pragma unroll
    for (int c = 0; c < 4; ++c) {
      wA[g][c] = *(const float4*)&pA[c * 4];
      wB[g][c] = *(const float4*)&pB[c * 4];
    }
  }

  const int ju = wv * 16 + (l & 15);     // reduce-phase unit (lanes<16)
  float c = 0.f;
  float x0 = 0.f, x1 = 0.f, x2 = 0.f, x3 = 0.f;
  if (l < 16) {                          // prefetch xw for s=0
    const int base = (b * 32 + 0) * 512 + ju;
    x0 = xw0[base +   0] + xw1[base +   0];
    x1 = xw0[base + 128] + xw1[base + 128];
    x2 = xw0[base + 256] + xw1[base + 256];
    x3 = xw0[base + 384] + xw1[base + 384];
  }
  // zero-init part[0] (== prologue dot with h(0)=0, bitwise identical)
  *(float4*)&part[0][wv][l * 4]       = make_float4(0.f, 0.f, 0.f, 0.f);
  *(float4*)&part[0][wv][256 + l * 4] = make_float4(0.f, 0.f, 0.f, 0.f);
  __syncthreads();

  for (int s = 0; s < 32; ++s) {
    float hn = 0.f;
    if (l < 16) {
      // prefetch next xw FIRST (in flight under exp chain + dot + barrier)
      float n0 = 0.f, n1 = 0.f, n2 = 0.f, n3 = 0.f;
      if (s < 31) {
        const int nb = (b * 32 + s + 1) * 512 + ju;
        n0 = xw0[nb +   0]; n1 = xw0[nb + 128];
        n2 = xw0[nb + 256]; n3 = xw0[nb + 384];
        n0 += xw1[nb +   0]; n1 += xw1[nb + 128];
        n2 += xw1[nb + 256]; n3 += xw1[nb + 384];
      }
      float g0 = x0, g1 = x1, g2 = x2, g3 = x3;
      #pragma unroll
      for (int w = 0; w < 8; ++w) {
        float4 p = *(const float4*)&part[s & 1][w][ju * 4];
        g0 += p.x; g1 += p.y; g2 += p.z; g3 += p.w;
      }
      float si = 1.f / (1.f + __expf(-g0));
      float sf = 1.f / (1.f + __expf(-g1));
      float tg = 1.f - 2.f / (1.f + __expf(2.f * g2));
      float so = 1.f / (1.f + __expf(-g3));
      c = sf * c + si * tg;
      float tc = 1.f - 2.f / (1.f + __expf(2.f * c));
      hn = so * tc;
      hist[s][ju] = hn;                  // epilogue-only; off critical path
      x0 = n0; x1 = n1; x2 = n2; x3 = n3;
    }
    // broadcast own-wave h via readlane (SGPRs; no LDS hop)
    if (s < 31) {
      float h00 = readl(hn,  0), h01 = readl(hn,  1), h02 = readl(hn,  2), h03 = readl(hn,  3);
      float h04 = readl(hn,  4), h05 = readl(hn,  5), h06 = readl(hn,  6), h07 = readl(hn,  7);
      float h08 = readl(hn,  8), h09 = readl(hn,  9), h10 = readl(hn, 10), h11 = readl(hn, 11);
      float h12 = readl(hn, 12), h13 = readl(hn, 13), h14 = readl(hn, 14), h15 = readl(hn, 15);
      float hv[4][4] = {{h00,h01,h02,h03},{h04,h05,h06,h07},
                        {h08,h09,h10,h11},{h12,h13,h14,h15}};
      float aA0=0.f,aA1=0.f,aA2=0.f,aA3=0.f,aB0=0.f,aB1=0.f,aB2=0.f,aB3=0.f;
      #pragma unroll
      for (int cc = 0; cc < 4; ++cc) {
        aA0 = fmaf(wA[0][cc].x, hv[cc][0], fmaf(wA[0][cc].y, hv[cc][1], fmaf(wA[0][cc].z, hv[cc][2], fmaf(wA[0][cc].w, hv[cc][3], aA0))));
        aA1 = fmaf(wA[1][cc].x, hv[cc][0], fmaf(wA[1][cc].y, hv[cc][1], fmaf(wA[1][cc].z, hv[cc][2], fmaf(wA[1][cc].w, hv[cc][3], aA1))));
        aA2 = fmaf(wA[2][cc].x, hv[cc][0], fmaf(wA[2][cc].y, hv[cc][1], fmaf(wA[2][cc].z, hv[cc][2], fmaf(wA[2][cc].w, hv[cc][3], aA2))));
        aA3 = fmaf(wA[3][cc].x, hv[cc][0], fmaf(wA[3][cc].y, hv[cc][1], fmaf(wA[3][cc].z, hv[cc][2], fmaf(wA[3][cc].w, hv[cc][3], aA3))));
        aB0 = fmaf(wB[0][cc].x, hv[cc][0], fmaf(wB[0][cc].y, hv[cc][1], fmaf(wB[0][cc].z, hv[cc][2], fmaf(wB[0][cc].w, hv[cc][3], aB0))));
        aB1 = fmaf(wB[1][cc].x, hv[cc][0], fmaf(wB[1][cc].y, hv[cc][1], fmaf(wB[1][cc].z, hv[cc][2], fmaf(wB[1][cc].w, hv[cc][3], aB1))));
        aB2 = fmaf(wB[2][cc].x, hv[cc][0], fmaf(wB[2][cc].y, hv[cc][1], fmaf(wB[2][cc].z, hv[cc][2], fmaf(wB[2][cc].w, hv[cc][3], aB2))));
        aB3 = fmaf(wB[3][cc].x, hv[cc][0], fmaf(wB[3][cc].y, hv[cc][1], fmaf(wB[3][cc].z, hv[cc][2], fmaf(wB[3][cc].w, hv[cc][3], aB3))));
      }
      *(float4*)&part[(s + 1) & 1][wv][l * 4]       = make_float4(aA0, aA1, aA2, aA3);
      *(float4*)&part[(s + 1) & 1][wv][256 + l * 4] = make_float4(aB0, aB1, aB2, aB3);
    }
    __syncthreads();                     // ONE barrier per step
  }

  // ================= staged mix epilogue =================
  const int word_base = b * 32;
  // stage w_lin transposed: wlT[u*17+d]
  {
    const int d = t >> 5, u0 = (t & 31) * 4;
    float4 v = *(const float4*)&w_lin[d * 128 + u0];
    wlT[(u0 + 0) * 17 + d] = v.x;
    wlT[(u0 + 1) * 17 + d] = v.y;
    wlT[(u0 + 2) * 17 + d] = v.z;
    wlT[(u0 + 3) * 17 + d] = v.w;
  }
  // stage the rest: 1032 float4s [w1|w2|w3|audio_b|b_lin b1 b2 b3]
  for (int i = t; i < 1032; i += 512) {
    const float* src;
    if (i < 296)       src = w1 + i * 4;
    else if (i < 360)  src = w2 + (i - 296) * 4;
    else if (i < 424)  src = w3 + (i - 360) * 4;
    else if (i < 1016) src = audio + word_base * 74 + (i - 424) * 4;
    else {
      int j = i - 1016;
      const float* bsrc = (j < 4) ? b_lin : (j < 8) ? b1 : (j < 12) ? b2 : b3;
      src = bsrc + (j & 3) * 4;
    }
    *(float4*)&stage[i * 4] = *(const float4*)src;
  }
  __syncthreads();

  const int s = t >> 4, d = t & 15;
  {
    float acc = stage[BLIN + d];
    const float* hh = &hist[s][0];
    for (int u = 0; u < 128; ++u) acc = fmaf(hh[u], wlT[u * 17 + d], acc);
    amp0s[s][d] = acc;
    float a = stage[B1O + d];
    const float* au = &stage[AUDO + s * 74];
    const float* w1r = &stage[W1O + d * 74];
    for (int k = 0; k < 74; ++k) a = fmaf(au[k], w1r[k], a);
    a1s[s][d] = fmaxf(a, 0.f);
  }
  __syncthreads();
  {
    float a = stage[B2O + d];
    #pragma unroll
    for (int k = 0; k < 16; ++k) a = fmaf(a1s[s][k], stage[W2O + d * 16 + k], a);
    a2s[s][d] = fmaxf(a, 0.f);
  }
  __syncthreads();
  {
    float a = stage[B3O + d];
    #pragma unroll
    for (int k = 0; k < 16; ++k) a = fmaf(a2s[s][k], stage[W3O + d * 16 + k], a);
    amp1s[s][d] = fmaxf(a, 0.f);
  }
  __syncthreads();
  if (t < 32) {
    float sq = 0.f;
    #pragma unroll
    for (int dd = 0; dd < 16; ++dd) sq += amp0s[t][dd] * amp0s[t][dd];
    nrm0[t] = sqrtf(sq);
  } else if (t >= 64 && t < 96) {
    int ss = t - 64;
    float sq = 0.f;
    #pragma unroll
    for (int dd = 0; dd < 16; ++dd) sq += amp1s[ss][dd] * amp1s[ss][dd];
    nrm1[ss] = sqrtf(sq);
  }
  __syncthreads();
  {
    const int word = widx[word_base + s];
    float k0 = amp0s[s][d] / (nrm0[s] + 1e-10f);
    float ph = ph0t[word * 16 + d];
    float cc = cosf(ph), sn = sinf(ph);
    tprs[s][d] = k0 * (cc - sn);        // r0 - i0
    tpis[s][d] = k0 * (cc + sn);        // r0 + i0
    float k1v = amp1s[s][d] / (nrm1[s] + 1e-10f);
    float p1 = ph1t[word * 16 + d];
    r1ss[s][d] = k1v * cosf(p1);
    i1ss[s][d] = k1v * sinf(p1);
    if (d == 0) {
      float e0 = __expf(modw[0]), e1 = __expf(modw[1]);
      float mw0 = e0 / (e0 + e1);
      ws[WT_OFF + word_base + s] = mw0 * nrm0[s] + (1.f - mw0) * nrm1[s];
    }
  }
  __syncthreads();
  {
    float* X = ws + XMAT_OFF;
    const int c2 = t;                    // column 0..511
    const int half = c2 >> 8;            // 0 = real, 1 = imag
    const int i2 = (c2 >> 4) & 15, j2 = c2 & 15;
    for (int ss = 0; ss < 32; ++ss) {
      float v;
      if (half == 0) v = tprs[ss][i2] * r1ss[ss][j2] - tpis[ss][i2] * i1ss[ss][j2];
      else           v = tprs[ss][i2] * i1ss[ss][j2] + tpis[ss][i2] * r1ss[ss][j2];
      X[(word_base + ss) * 512 + c2] = v;
    }
  }
}

// =====================================================================
// K4: P[r][c] = sum_k X[r][k] * V''[c][k]   (1024 x 256, k=512 split x4)
// =====================================================================
__global__ __launch_bounds__(256) void k4_meas(float* __restrict__ ws)
{
  const int bid = blockIdx.x, t = threadIdx.x;
  const int rb = bid & 15, cb = (bid >> 4) & 3, kq = bid >> 6;
  const int R = rb * 64, C = cb * 64;
  const float* X = ws + XMAT_OFF;
  const float* V = ws + VPP_OFF;
  __shared__ alignas(16) float Xs[32][68];
  __shared__ alignas(16) float Vs[32][68];
  float acc[4][4] = {};
  const int r0 = (t & 15) * 4, j0 = (t >> 4) * 4;

  for (int kt = 0; kt < 4; ++kt) {
    #pragma unroll
    for (int pass = 0; pass < 2; ++pass) {
      int rr = (t >> 3) + pass * 32;
      int kk4 = (t & 7) * 4;
      int gk = kq * 128 + kt * 32 + kk4;
      float4 xv = *(const float4*)&X[(R + rr) * 512 + gk];
      float4 vv = *(const float4*)&V[(C + rr) * 512 + gk];
      Xs[kk4 + 0][rr] = xv.x; Xs[kk4 + 1][rr] = xv.y;
      Xs[kk4 + 2][rr] = xv.z; Xs[kk4 + 3][rr] = xv.w;
      Vs[kk4 + 0][rr] = vv.x; Vs[kk4 + 1][rr] = vv.y;
      Vs[kk4 + 2][rr] = vv.z; Vs[kk4 + 3][rr] = vv.w;
    }
    __syncthreads();
    #pragma unroll
    for (int k = 0; k < 32; ++k) {
      float4 a4 = *(const float4*)&Xs[k][r0];
      float4 w4 = *(const float4*)&Vs[k][j0];
      float ar[4] = {a4.x, a4.y, a4.z, a4.w};
      float wr[4] = {w4.x, w4.y, w4.z, w4.w};
      #pragma unroll
      for (int i2 = 0; i2 < 4; ++i2)
        #pragma unroll
        for (int j2 = 0; j2 < 4; ++j2)
          acc[i2][j2] = fmaf(ar[i2], wr[j2], acc[i2][j2]);
    }
    __syncthreads();
  }
  float* Pp = ws + PP_OFF + (unsigned)kq * PP_HALF;
  #pragma unroll
  for (int i2 = 0; i2 < 4; ++i2) {
    float4 v = make_float4(acc[i2][0], acc[i2][1], acc[i2][2], acc[i2][3]);
    *(float4*)&Pp[(R + r0 + i2) * 256 + C + j0] = v;
  }
}

// =====================================================================
// K5: per b: p[s][u] = P[2u]^2 + P[2u+1]^2 (sum kq partials);
//     n-gram softmax mixes (n=1,3 zero-padded), max-pool, final MLP.
// =====================================================================
__global__ __launch_bounds__(512) void k5_final(
    const float* __restrict__ fw1, const float* __restrict__ fb1,
    const float* __restrict__ fw2, const float* __restrict__ fb2,
    const float* __restrict__ fw3, const float* __restrict__ fb3,
    const float* __restrict__ ws, float* __restrict__ out)
{
  const int b = blockIdx.x, t = threadIdx.x;
  const int u = t & 127, sg = t >> 7;      // sg 0..3
  __shared__ float ewt[34];
  __shared__ float pl[32][128];
  __shared__ float fred[4][128];
  __shared__ float feat[128], y1[64], y2[64];
  if (t < 32) ewt[t] = __expf(ws[WT_OFF + b * 32 + t]);
  if (t >= 32 && t < 34) ewt[t] = 1.f;
  __syncthreads();

  const float* Pp = ws + PP_OFF;
  #pragma unroll
  for (int i = 0; i < 8; ++i) {
    int s = sg * 8 + i;
    int bs = b * 32 + s;
    float A = 0.f, Bv = 0.f;
    #pragma unroll
    for (int kq = 0; kq < 4; ++kq) {
      A  += Pp[kq * PP_HALF + bs * 256 + 2 * u];
      Bv += Pp[kq * PP_HALF + bs * 256 + 2 * u + 1];
    }
    pl[s][u] = A * A + Bv * Bv;
  }
  __syncthreads();

  float m = -1e30f;
  #pragma unroll
  for (int i = 0; i < 8; ++i) {
    int s = sg * 8 + i;
    float p0 = pl[s][u];
    m = fmaxf(m, p0);
    float e0 = ewt[s], e1 = ewt[s + 1], e2 = ewt[s + 2];
    float num = e0 * p0;
    if (s + 1 < 32) num += e1 * pl[s + 1][u];
    if (s + 2 < 32) num += e2 * pl[s + 2][u];
    m = fmaxf(m, num / (e0 + e1 + e2));
  }
  fred[sg][u] = m;
  __syncthreads();
  if (t < 128)
    feat[t] = fmaxf(fmaxf(fred[0][t], fred[1][t]), fmaxf(fred[2][t], fred[3][t]));
  __syncthreads();
  if (t < 64) {
    float acc = fb1[t];
    for (int k = 0; k < 128; ++k) acc = fmaf(feat[k], fw1[t * 128 + k], acc);
    y1[t] = fmaxf(acc, 0.f);
  }
  __syncthreads();
  if (t < 64) {
    float acc = fb2[t];
    #pragma unroll
    for (int k = 0; k < 64; ++k) acc = fmaf(y1[k], fw2[t * 64 + k], acc);
    y2[t] = fmaxf(acc, 0.f);
  }
  __syncthreads();
  if (t == 0) {
    float acc = fb3[0];
    #pragma unroll
    for (int k = 0; k < 64; ++k) acc = fmaf(y2[k], fw3[k], acc);
    out[b] = acc;
  }
}

// =====================================================================
extern "C" void kernel_launch(void* const* d_in, const int* in_sizes, int n_in,
                              void* d_out, int out_size, void* d_ws, size_t ws_size,
                              hipStream_t stream) {
  const int*   widx  = (const int*)d_in[0];
  const float* audio = (const float*)d_in[1];
  const float* lut   = (const float*)d_in[2];
  const float* ph0   = (const float*)d_in[3];
  const float* ph1   = (const float*)d_in[4];
  const float* w_ih  = (const float*)d_in[5];
  const float* w_hh  = (const float*)d_in[6];
  const float* b_ih  = (const float*)d_in[7];
  const float* b_hh  = (const float*)d_in[8];
  const float* w_lin = (const float*)d_in[9];
  const float* b_lin = (const float*)d_in[10];
  const float* w1    = (const float*)d_in[11];
  const float* b1    = (const float*)d_in[12];
  const float* w2    = (const float*)d_in[13];
  const float* b2    = (const float*)d_in[14];
  const float* w3    = (const float*)d_in[15];
  const float* b3    = (const float*)d_in[16];
  const float* modw  = (const float*)d_in[17];
  const float* mr    = (const float*)d_in[18];
  const float* mi    = (const float*)d_in[19];
  const float* fw1   = (const float*)d_in[20];
  const float* fb1   = (const float*)d_in[21];
  const float* fw2   = (const float*)d_in[22];
  const float* fb2   = (const float*)d_in[23];
  const float* fw3   = (const float*)d_in[24];
  const float* fb3   = (const float*)d_in[25];
  float* ws  = (float*)d_ws;
  float* out = (float*)d_out;

  k1_xw_gemm<<<dim3(384), dim3(256), 0, stream>>>(widx, lut, w_ih, b_ih, b_hh, mr, mi, ws);
  k2_lstm_mix<<<dim3(32), dim3(512), 0, stream>>>(w_hh, widx, audio, ph0, ph1,
                                                  w_lin, b_lin, w1, b1, w2, b2,
                                                  w3, b3, modw, ws);
  k4_meas<<<dim3(256), dim3(256), 0, stream>>>(ws);
  k5_final<<<dim3(32), dim3(512), 0, stream>>>(fw1, fb1, fw2, fb2, fw3, fb3, ws, out);
}